// Round 5
// baseline (2799.222 us; speedup 1.0000x reference)
//
#include <hip/hip_runtime.h>
#include <math.h>

#define N_NODES 100000
#define N_EDGES 1600000
#define EP (N_EDGES + N_NODES)   // edges + self-loops = 1,700,000
#define NH 8
#define NC 64
#define NG 64
#define HC 512
#define SCAN_BLOCKS ((N_NODES + 255) / 256)   // 391
#define NPART 32                              // pooling atomic partitions
#define ASTRIDE 56                            // LDS row stride (shorts) for GEMM tiles

typedef unsigned short bf16_t;
typedef __attribute__((ext_vector_type(8))) short short8;
typedef __attribute__((ext_vector_type(4))) float floatx4;

__device__ inline float bf2f(bf16_t u) {
    union { unsigned int i; float f; } x;
    x.i = (unsigned int)u << 16;
    return x.f;
}
__device__ inline bf16_t f2bf(float f) {
    union { float f; unsigned int i; } x;
    x.f = f;
    unsigned int b = x.i;
    return (bf16_t)((b + 0x7fffu + ((b >> 16) & 1u)) >> 16);
}
__device__ inline float u2flo(unsigned int u) {
    union { unsigned int i; float f; } x;
    x.i = u << 16;
    return x.f;
}
__device__ inline float u2fhi(unsigned int u) {
    union { unsigned int i; float f; } x;
    x.i = u & 0xffff0000u;
    return x.f;
}

// ---------------- prep: ws1[h][k] = sum_c W1[k][h*64+c]*a1s[h][c]; wd1 likewise ----------------
__global__ void k_prep(const float* __restrict__ W1, const float* __restrict__ a1s,
                       const float* __restrict__ a1d, float* __restrict__ wprep) {
    int t = threadIdx.x;  // need 48
    if (t < 48) {
        int isD = t >= 24;
        int tt = t % 24;
        int h = tt / 3, k = tt % 3;
        const float* a = isD ? a1d : a1s;
        float s = 0.f;
        for (int c = 0; c < 64; c++) s += W1[k * HC + h * 64 + c] * a[h * 64 + c];
        wprep[t] = s;  // [0..23]=ws1[h*3+k], [24..47]=wd1
    }
}

// ---------------- CSR build ----------------
__global__ void k_deg(const int* __restrict__ ei, int* __restrict__ deg) {
    int i = blockIdx.x * 256 + threadIdx.x;
    if (i >= EP) return;
    int d = (i < N_EDGES) ? ei[N_EDGES + i] : (i - N_EDGES);
    atomicAdd(&deg[d], 1);
}

__global__ void k_scan1(const int* __restrict__ deg, int* __restrict__ rowptr, int* __restrict__ part) {
    __shared__ int s[256];
    int t = threadIdx.x, i = blockIdx.x * 256 + t;
    int v = (i < N_NODES) ? deg[i] : 0;
    s[t] = v;
    __syncthreads();
    for (int off = 1; off < 256; off <<= 1) {
        int u = (t >= off) ? s[t - off] : 0;
        __syncthreads();
        s[t] += u;
        __syncthreads();
    }
    if (i < N_NODES) rowptr[i] = s[t] - v;  // exclusive
    if (t == 255) part[blockIdx.x] = s[t];
}

__global__ void k_scan2(int* __restrict__ part, int* __restrict__ rowptr) {
    __shared__ int s[512];
    int t = threadIdx.x;
    int v = (t < SCAN_BLOCKS) ? part[t] : 0;
    s[t] = v;
    __syncthreads();
    for (int off = 1; off < 512; off <<= 1) {
        int u = (t >= off) ? s[t - off] : 0;
        __syncthreads();
        s[t] += u;
        __syncthreads();
    }
    part[t] = s[t] - v;  // exclusive
    if (t == 0) rowptr[N_NODES] = EP;
}

__global__ void k_scan3(const int* __restrict__ part, int* __restrict__ rowptr, int* __restrict__ cursor) {
    int i = blockIdx.x * 256 + threadIdx.x;
    if (i < N_NODES) {
        int v = rowptr[i] + part[blockIdx.x];
        rowptr[i] = v;
        cursor[i] = v;   // scatter cursor starts at row base (no memset needed)
    }
}

__global__ void k_scatter(const int* __restrict__ ei, int* __restrict__ cursor, int* __restrict__ csr) {
    int i = blockIdx.x * 256 + threadIdx.x;
    if (i >= EP) return;
    int s, d;
    if (i < N_EDGES) { s = ei[i]; d = ei[N_EDGES + i]; }
    else { s = i - N_EDGES; d = s; }
    int pos = atomicAdd(&cursor[d], 1);
    csr[pos] = s;
}

// ---------------- W2 -> bf16 transposed with k-permutation matching x1p layout ----------------
// x1p[.][kp] = x1[.][(kp&7)*64 + (kp>>3)]  =>  W2T[n][kp] = W2[(kp&7)*64 + (kp>>3)][n]
__global__ void k_w2t(const float* __restrict__ W2, bf16_t* __restrict__ W2T) {
    int i = blockIdx.x * 256 + threadIdx.x;  // over 512*512
    int n = i >> 9, kp = i & 511;
    int k = (kp & 7) * 64 + (kp >> 3);
    W2T[i] = f2bf(W2[k * HC + n]);
}

// ---------------- layer 1: single-pass softmax (logits provably tiny, no max shift) ---------
// output stored k-PERMUTED: x1p[dst][lane*8+h] = x1[dst][h*64+lane]  (uint4 store)
__global__ __launch_bounds__(256) void k_layer1(
    const float* __restrict__ x, const int* __restrict__ rowptr, const int* __restrict__ csr,
    const float* __restrict__ W1, const float* __restrict__ wprep, const float* __restrict__ b1,
    bf16_t* __restrict__ x1p) {
    __shared__ float w1s[1536];
    __shared__ float wp[48];
    int tid = threadIdx.x;
    for (int i = tid; i < 1536; i += 256) w1s[i] = W1[i];
    if (tid < 48) wp[tid] = wprep[tid];
    __syncthreads();
    int lane = tid & 63;
    int dst = (blockIdx.x * 256 + tid) >> 6;
    int rs = rowptr[dst], re = rowptr[dst + 1];
    float xd0 = x[dst * 3], xd1 = x[dst * 3 + 1], xd2 = x[dst * 3 + 2];
    float ald[NH];
#pragma unroll
    for (int h = 0; h < NH; h++)
        ald[h] = xd0 * wp[24 + h * 3] + xd1 * wp[24 + h * 3 + 1] + xd2 * wp[24 + h * 3 + 2];
    float den[NH], c0[NH], c1[NH], c2[NH];
#pragma unroll
    for (int h = 0; h < NH; h++) { den[h] = 0.f; c0[h] = 0.f; c1[h] = 0.f; c2[h] = 0.f; }
    for (int base = rs; base < re; base += 64) {
        int e = base + lane;
        if (e < re) {
            int s = csr[e];
            float s0 = x[s * 3], s1 = x[s * 3 + 1], s2 = x[s * 3 + 2];
#pragma unroll
            for (int h = 0; h < NH; h++) {
                float ev = s0 * wp[h * 3] + s1 * wp[h * 3 + 1] + s2 * wp[h * 3 + 2] + ald[h];
                ev = fmaxf(ev, 0.2f * ev);
                float w = __expf(ev);      // |ev| <= ~1.2, no overflow risk
                den[h] += w;
                c0[h] += w * s0;
                c1[h] += w * s1;
                c2[h] += w * s2;
            }
        }
    }
#pragma unroll
    for (int h = 0; h < NH; h++) {
#pragma unroll
        for (int off = 1; off < 64; off <<= 1) {
            den[h] += __shfl_xor(den[h], off, 64);
            c0[h] += __shfl_xor(c0[h], off, 64);
            c1[h] += __shfl_xor(c1[h], off, 64);
            c2[h] += __shfl_xor(c2[h], off, 64);
        }
    }
    bf16_t vb[NH];
#pragma unroll
    for (int h = 0; h < NH; h++) {
        int col = h * 64 + lane;
        float v = c0[h] * w1s[col] + c1[h] * w1s[512 + col] + c2[h] * w1s[1024 + col];
        v = v / den[h] + b1[col];
        v = v > 0.f ? v : (__expf(v) - 1.f);
        vb[h] = f2bf(v);
    }
    uint4 o;
    o.x = (unsigned int)vb[0] | ((unsigned int)vb[1] << 16);
    o.y = (unsigned int)vb[2] | ((unsigned int)vb[3] << 16);
    o.z = (unsigned int)vb[4] | ((unsigned int)vb[5] << 16);
    o.w = (unsigned int)vb[6] | ((unsigned int)vb[7] << 16);
    *(uint4*)&x1p[(size_t)dst * HC + lane * 8] = o;
}

// ---------------- GEMM2: h2 = x1p @ W2 (bf16 MFMA), NATURAL col output (coalesced) ----------
__global__ __launch_bounds__(256) void k_gemm2(const bf16_t* __restrict__ A,
                                               const bf16_t* __restrict__ BT,
                                               bf16_t* __restrict__ Out,
                                               int row_base, int nrows) {
    __shared__ short As[128 * ASTRIDE];
    __shared__ short Bs[128 * ASTRIDE];
    int tid = threadIdx.x;
    int lane = tid & 63, wave = tid >> 6;
    int wm = wave & 1, wn = wave >> 1;
    int lm = lane & 15, quad = lane >> 4;
    int gx = blockIdx.x, gy = blockIdx.y;
    floatx4 acc[4][4];
#pragma unroll
    for (int mi = 0; mi < 4; mi++)
#pragma unroll
        for (int ni = 0; ni < 4; ni++) acc[mi][ni] = (floatx4){0.f, 0.f, 0.f, 0.f};

    for (int k0 = 0; k0 < HC; k0 += 32) {
        uint4 av[2], bv[2];
        int rr[2], pp[2];
#pragma unroll
        for (int q = 0; q < 2; q++) {
            int c = tid * 2 + q;
            rr[q] = c >> 2;
            pp[q] = c & 3;
            int grow = gy * 128 + rr[q];
            if (grow < nrows)
                av[q] = *(const uint4*)&A[(size_t)(row_base + grow) * HC + k0 + pp[q] * 8];
            else { av[q].x = 0u; av[q].y = 0u; av[q].z = 0u; av[q].w = 0u; }
            bv[q] = *(const uint4*)&BT[(size_t)(gx * 128 + rr[q]) * HC + k0 + pp[q] * 8];
        }
        __syncthreads();
#pragma unroll
        for (int q = 0; q < 2; q++) {
            *(uint4*)&As[rr[q] * ASTRIDE + pp[q] * 8] = av[q];
            *(uint4*)&Bs[rr[q] * ASTRIDE + pp[q] * 8] = bv[q];
        }
        __syncthreads();
        short8 af[4], bf[4];
#pragma unroll
        for (int mi = 0; mi < 4; mi++)
            af[mi] = *(const short8*)&As[(wm * 64 + mi * 16 + lm) * ASTRIDE + quad * 8];
#pragma unroll
        for (int ni = 0; ni < 4; ni++)
            bf[ni] = *(const short8*)&Bs[(wn * 64 + ni * 16 + lm) * ASTRIDE + quad * 8];
#pragma unroll
        for (int mi = 0; mi < 4; mi++)
#pragma unroll
            for (int ni = 0; ni < 4; ni++)
                acc[mi][ni] = __builtin_amdgcn_mfma_f32_16x16x32_bf16(af[mi], bf[ni], acc[mi][ni], 0, 0, 0);
    }
    // epilogue: C row = quad*4+reg (m), col = natural n (consecutive across lm -> coalesced)
#pragma unroll
    for (int mi = 0; mi < 4; mi++)
#pragma unroll
        for (int ni = 0; ni < 4; ni++) {
            int col = gx * 128 + wn * 64 + ni * 16 + lm;
#pragma unroll
            for (int rg = 0; rg < 4; rg++) {
                int lrow = gy * 128 + wm * 64 + mi * 16 + quad * 4 + rg;
                if (lrow < nrows) Out[(size_t)lrow * HC + col] = f2bf(acc[mi][ni][rg]);
            }
        }
}

// ---------------- al2: per-node logits from NATURAL h2 (read-only) ----------------
// lane covers channels lane*8..lane*8+7, all of head hme = lane>>3
__global__ __launch_bounds__(256) void k_al2(const bf16_t* __restrict__ h2,
                                             const float* __restrict__ a2s,
                                             const float* __restrict__ a2d,
                                             float* __restrict__ al2s, float* __restrict__ al2d) {
    int tid = threadIdx.x, lane = tid & 63, wave = tid >> 6;
    int node = blockIdx.x * 4 + wave;
    uint4 v = *(const uint4*)&h2[(size_t)node * HC + lane * 8];
    float f[8] = {u2flo(v.x), u2fhi(v.x), u2flo(v.y), u2fhi(v.y),
                  u2flo(v.z), u2fhi(v.z), u2flo(v.w), u2fhi(v.w)};
    float4 sa = *(const float4*)&a2s[lane * 8];
    float4 sb = *(const float4*)&a2s[lane * 8 + 4];
    float4 da = *(const float4*)&a2d[lane * 8];
    float4 db = *(const float4*)&a2d[lane * 8 + 4];
    float ps = f[0] * sa.x + f[1] * sa.y + f[2] * sa.z + f[3] * sa.w
             + f[4] * sb.x + f[5] * sb.y + f[6] * sb.z + f[7] * sb.w;
    float pd = f[0] * da.x + f[1] * da.y + f[2] * da.z + f[3] * da.w
             + f[4] * db.x + f[5] * db.y + f[6] * db.z + f[7] * db.w;
#pragma unroll
    for (int off = 1; off < 8; off <<= 1) {   // reduce within 8-lane head group
        ps += __shfl_xor(ps, off, 64);
        pd += __shfl_xor(pd, off, 64);
    }
    if ((lane & 7) == 0) {
        al2s[node * NH + (lane >> 3)] = ps;
        al2d[node * NH + (lane >> 3)] = pd;
    }
}

// ---------------- layer 2 (NATURAL layout): softmax + aggregation + fused mean-pool ---------
__global__ __launch_bounds__(256) void k_layer2pool(
    const bf16_t* __restrict__ h2, const float* __restrict__ al2s, const float* __restrict__ al2d,
    const int* __restrict__ rowptr, const int* __restrict__ csr, const float* __restrict__ b2,
    const int* __restrict__ batch, float* __restrict__ poolpart) {
    __shared__ float wlds[4][512];
    __shared__ int slds[4][64];
    int tid = threadIdx.x, lane = tid & 63, wave = tid >> 6;
    int hme = lane >> 3;
    int dst = blockIdx.x * 4 + wave;
    int rs = rowptr[dst], re = rowptr[dst + 1];
    float4 d0 = *(const float4*)&al2d[dst * NH];
    float4 d1 = *(const float4*)&al2d[dst * NH + 4];
    float ald[NH] = {d0.x, d0.y, d0.z, d0.w, d1.x, d1.y, d1.z, d1.w};
    float den[NH], acc[8];
#pragma unroll
    for (int h = 0; h < NH; h++) den[h] = 0.f;
#pragma unroll
    for (int q = 0; q < 8; q++) acc[q] = 0.f;
    for (int base = rs; base < re; base += 64) {
        int e = base + lane;
        int cl = re - base; if (cl > 64) cl = 64;
        float w[NH];
        int s = 0;
        if (e < re) {
            s = csr[e];
            float4 p0 = *(const float4*)&al2s[s * NH];
            float4 p1 = *(const float4*)&al2s[s * NH + 4];
            float als[NH] = {p0.x, p0.y, p0.z, p0.w, p1.x, p1.y, p1.z, p1.w};
#pragma unroll
            for (int h = 0; h < NH; h++) {
                float ev = als[h] + ald[h];
                ev = fmaxf(ev, 0.2f * ev);
                w[h] = __expf(ev);        // |ev| small, no overflow risk
                den[h] += w[h];
            }
        } else {
#pragma unroll
            for (int h = 0; h < NH; h++) w[h] = 0.f;
        }
        slds[wave][lane] = s;
        *(float4*)&wlds[wave][lane * 8] = make_float4(w[0], w[1], w[2], w[3]);
        *(float4*)&wlds[wave][lane * 8 + 4] = make_float4(w[4], w[5], w[6], w[7]);
        // same-wave LDS write->read in program order; scalar weight broadcast per lane group
        int j = 0;
        for (; j + 3 < cl; j += 4) {
            int s0 = slds[wave][j + 0], s1 = slds[wave][j + 1];
            int s2 = slds[wave][j + 2], s3 = slds[wave][j + 3];
            float w0 = wlds[wave][(j + 0) * 8 + hme];
            float w1 = wlds[wave][(j + 1) * 8 + hme];
            float w2 = wlds[wave][(j + 2) * 8 + hme];
            float w3 = wlds[wave][(j + 3) * 8 + hme];
            uint4 v0 = *(const uint4*)&h2[(size_t)s0 * HC + lane * 8];
            uint4 v1 = *(const uint4*)&h2[(size_t)s1 * HC + lane * 8];
            uint4 v2 = *(const uint4*)&h2[(size_t)s2 * HC + lane * 8];
            uint4 v3 = *(const uint4*)&h2[(size_t)s3 * HC + lane * 8];
            acc[0] += w0 * u2flo(v0.x); acc[1] += w0 * u2fhi(v0.x);
            acc[2] += w0 * u2flo(v0.y); acc[3] += w0 * u2fhi(v0.y);
            acc[4] += w0 * u2flo(v0.z); acc[5] += w0 * u2fhi(v0.z);
            acc[6] += w0 * u2flo(v0.w); acc[7] += w0 * u2fhi(v0.w);
            acc[0] += w1 * u2flo(v1.x); acc[1] += w1 * u2fhi(v1.x);
            acc[2] += w1 * u2flo(v1.y); acc[3] += w1 * u2fhi(v1.y);
            acc[4] += w1 * u2flo(v1.z); acc[5] += w1 * u2fhi(v1.z);
            acc[6] += w1 * u2flo(v1.w); acc[7] += w1 * u2fhi(v1.w);
            acc[0] += w2 * u2flo(v2.x); acc[1] += w2 * u2fhi(v2.x);
            acc[2] += w2 * u2flo(v2.y); acc[3] += w2 * u2fhi(v2.y);
            acc[4] += w2 * u2flo(v2.z); acc[5] += w2 * u2fhi(v2.z);
            acc[6] += w2 * u2flo(v2.w); acc[7] += w2 * u2fhi(v2.w);
            acc[0] += w3 * u2flo(v3.x); acc[1] += w3 * u2fhi(v3.x);
            acc[2] += w3 * u2flo(v3.y); acc[3] += w3 * u2fhi(v3.y);
            acc[4] += w3 * u2flo(v3.z); acc[5] += w3 * u2fhi(v3.z);
            acc[6] += w3 * u2flo(v3.w); acc[7] += w3 * u2fhi(v3.w);
        }
        for (; j < cl; j++) {
            int sA = slds[wave][j];
            float wA = wlds[wave][j * 8 + hme];
            uint4 vA = *(const uint4*)&h2[(size_t)sA * HC + lane * 8];
            acc[0] += wA * u2flo(vA.x); acc[1] += wA * u2fhi(vA.x);
            acc[2] += wA * u2flo(vA.y); acc[3] += wA * u2fhi(vA.y);
            acc[4] += wA * u2flo(vA.z); acc[5] += wA * u2fhi(vA.z);
            acc[6] += wA * u2flo(vA.w); acc[7] += wA * u2fhi(vA.w);
        }
    }
#pragma unroll
    for (int h = 0; h < NH; h++)
#pragma unroll
        for (int off = 1; off < 64; off <<= 1) den[h] += __shfl_xor(den[h], off, 64);
    // select this lane's head denominator (no dynamic register indexing)
    float dd = den[0];
#pragma unroll
    for (int h = 1; h < NH; h++) dd = (hme == h) ? den[h] : dd;
    float dinv = 1.0f / dd;
    int g = batch[dst];
    float* pp = poolpart + ((size_t)(blockIdx.x & (NPART - 1)) * NG + g) * HC;
    float4 ba = *(const float4*)&b2[lane * 8];
    float4 bb = *(const float4*)&b2[lane * 8 + 4];
    float bv[8] = {ba.x, ba.y, ba.z, ba.w, bb.x, bb.y, bb.z, bb.w};
#pragma unroll
    for (int q = 0; q < 8; q++) {
        float v = acc[q] * dinv + bv[q];
        v = v > 0.f ? v : (__expf(v) - 1.f);
        atomicAdd(&pp[lane * 8 + q], v);
    }
}

// ---------------- graph bounds ----------------
__global__ void k_initb(int* __restrict__ gstart) {
    int i = blockIdx.x * 64 + threadIdx.x;
    if (i <= NG) gstart[i] = N_NODES;
}

__global__ void k_bounds(const int* __restrict__ batch, int* __restrict__ gstart) {
    int i = blockIdx.x * 256 + threadIdx.x;
    if (i >= N_NODES) return;
    int b = batch[i];
    if (i == 0) {
        for (int g = 0; g <= b; g++) gstart[g] = 0;
    } else {
        int bp = batch[i - 1];
        if (b != bp)
            for (int g = bp + 1; g <= b; g++) gstart[g] = i;
    }
}

// ---------------- reduce pooling partitions ----------------
__global__ void k_poolred(const float* __restrict__ poolpart, float* __restrict__ pooled) {
    int i = blockIdx.x * 256 + threadIdx.x;
    if (i >= NG * HC) return;
    float s = 0.f;
    for (int p = 0; p < NPART; p++) s += poolpart[(size_t)p * NG * HC + i];
    pooled[i] = s;
}

// ---------------- classifier ----------------
__global__ void k_cls(const float* __restrict__ pooled, const int* __restrict__ gstart,
                      const float* __restrict__ Wc, const float* __restrict__ bc,
                      float* __restrict__ out) {
    int i = blockIdx.x * 256 + threadIdx.x;
    if (i >= NG * 10) return;
    int g = i / 10, o = i % 10;
    float cnt = fmaxf((float)(gstart[g + 1] - gstart[g]), 1.0f);
    float acc = 0.f;
    for (int k = 0; k < HC; k++) acc += pooled[g * HC + k] * Wc[k * 10 + o];
    out[i] = acc / cnt + bc[o];
}

extern "C" void kernel_launch(void* const* d_in, const int* in_sizes, int n_in,
                              void* d_out, int out_size, void* d_ws, size_t ws_size,
                              hipStream_t stream) {
    const float* x   = (const float*)d_in[0];
    const int*   ei  = (const int*)d_in[1];
    const int*   bat = (const int*)d_in[2];
    const float* W1  = (const float*)d_in[3];
    const float* a1s = (const float*)d_in[4];
    const float* a1d = (const float*)d_in[5];
    const float* b1  = (const float*)d_in[6];
    const float* W2  = (const float*)d_in[7];
    const float* a2s = (const float*)d_in[8];
    const float* a2d = (const float*)d_in[9];
    const float* b2  = (const float*)d_in[10];
    const float* Wc  = (const float*)d_in[11];
    const float* bc  = (const float*)d_in[12];
    float* out = (float*)d_out;

    char* ws = (char*)d_ws;
    size_t off = 0;
    auto alloc = [&](size_t bytes) {
        size_t o = off;
        off += (bytes + 255) & ~(size_t)255;
        return o;
    };
    float*  wprep    = (float*)(ws + alloc(48 * 4));
    int*    rowptr   = (int*)(ws + alloc((size_t)(N_NODES + 1) * 4));
    int*    deg      = (int*)(ws + alloc((size_t)N_NODES * 4));
    int*    cursor   = (int*)(ws + alloc((size_t)N_NODES * 4));
    int*    part     = (int*)(ws + alloc(512 * 4));
    int*    gstart   = (int*)(ws + alloc(65 * 4));
    int*    csr      = (int*)(ws + alloc((size_t)EP * 4));
    bf16_t* x1b      = (bf16_t*)(ws + alloc((size_t)N_NODES * HC * 2));
    float*  al2s     = (float*)(ws + alloc((size_t)N_NODES * NH * 4));
    float*  al2d     = (float*)(ws + alloc((size_t)N_NODES * NH * 4));
    float*  poolpart = (float*)(ws + alloc((size_t)NPART * NG * HC * 4));
    float*  pooled   = (float*)(ws + alloc((size_t)NG * HC * 4));
    // W2T (512KB) aliases deg+cursor (800KB, dead after k_scatter)
    bf16_t* W2T = (bf16_t*)deg;

    size_t rem = (ws_size > off) ? ws_size - off : 0;
    int nslices, srows;
    if (rem >= (size_t)N_NODES * HC * 2)      { nslices = 1;  srows = N_NODES; }
    else if (rem >= (size_t)25000 * HC * 2)   { nslices = 4;  srows = 25000; }
    else                                      { nslices = 16; srows = 6250; }
    bf16_t* T = (bf16_t*)(ws + alloc((size_t)srows * HC * 2));
    bf16_t* h2 = (nslices == 1) ? T : x1b;

    hipMemsetAsync(deg, 0, (size_t)N_NODES * 4, stream);
    hipMemsetAsync(poolpart, 0, (size_t)NPART * NG * HC * 4, stream);

    k_prep<<<1, 64, 0, stream>>>(W1, a1s, a1d, wprep);
    k_deg<<<(EP + 255) / 256, 256, 0, stream>>>(ei, deg);
    k_scan1<<<SCAN_BLOCKS, 256, 0, stream>>>(deg, rowptr, part);
    k_scan2<<<1, 512, 0, stream>>>(part, rowptr);
    k_scan3<<<SCAN_BLOCKS, 256, 0, stream>>>(part, rowptr, cursor);
    k_scatter<<<(EP + 255) / 256, 256, 0, stream>>>(ei, cursor, csr);
    k_w2t<<<(HC * HC + 255) / 256, 256, 0, stream>>>(W2, W2T);  // aliases deg/cursor (dead)
    k_layer1<<<N_NODES / 4, 256, 0, stream>>>(x, rowptr, csr, W1, wprep, b1, x1b);
    if (nslices == 1) {
        k_gemm2<<<dim3(4, (N_NODES + 127) / 128), 256, 0, stream>>>(x1b, W2T, h2, 0, N_NODES);
    } else {
        for (int s = 0; s < nslices; s++) {
            k_gemm2<<<dim3(4, (srows + 127) / 128), 256, 0, stream>>>(x1b, W2T, T, s * srows, srows);
            hipMemcpyAsync(x1b + (size_t)s * srows * HC, T, (size_t)srows * HC * 2,
                           hipMemcpyDeviceToDevice, stream);
        }
    }
    k_al2<<<N_NODES / 4, 256, 0, stream>>>(h2, a2s, a2d, al2s, al2d);
    k_initb<<<2, 64, 0, stream>>>(gstart);
    k_bounds<<<SCAN_BLOCKS, 256, 0, stream>>>(bat, gstart);
    k_layer2pool<<<N_NODES / 4, 256, 0, stream>>>(h2, al2s, al2d, rowptr, csr, b2, bat, poolpart);
    k_poolred<<<(NG * HC + 255) / 256, 256, 0, stream>>>(poolpart, pooled);
    k_cls<<<3, 256, 0, stream>>>(pooled, gstart, Wc, bc, out);
}

// Round 6
// 1059.288 us; speedup vs baseline: 2.6426x; 2.6426x over previous
//
#include <hip/hip_runtime.h>
#include <math.h>

#define N_NODES 100000
#define N_EDGES 1600000
#define EP (N_EDGES + N_NODES)   // edges + self-loops = 1,700,000
#define NH 8
#define NC 64
#define NG 64
#define HC 512
#define SCAN_BLOCKS ((N_NODES + 255) / 256)   // 391
#define NPART 32                              // pooling atomic partitions
#define ASTRIDE 56                            // LDS row stride (shorts) for GEMM tiles

typedef unsigned short bf16_t;
typedef __attribute__((ext_vector_type(8))) short short8;
typedef __attribute__((ext_vector_type(4))) float floatx4;

__device__ inline float bf2f(bf16_t u) {
    union { unsigned int i; float f; } x;
    x.i = (unsigned int)u << 16;
    return x.f;
}
__device__ inline bf16_t f2bf(float f) {
    union { float f; unsigned int i; } x;
    x.f = f;
    unsigned int b = x.i;
    return (bf16_t)((b + 0x7fffu + ((b >> 16) & 1u)) >> 16);
}
__device__ inline float u2flo(unsigned int u) {
    union { unsigned int i; float f; } x;
    x.i = u << 16;
    return x.f;
}
__device__ inline float u2fhi(unsigned int u) {
    union { unsigned int i; float f; } x;
    x.i = u & 0xffff0000u;
    return x.f;
}

// ---------------- prep: ws1[h][k] = sum_c W1[k][h*64+c]*a1s[h][c]; wd1 likewise ----------------
__global__ void k_prep(const float* __restrict__ W1, const float* __restrict__ a1s,
                       const float* __restrict__ a1d, float* __restrict__ wprep) {
    int t = threadIdx.x;  // need 48
    if (t < 48) {
        int isD = t >= 24;
        int tt = t % 24;
        int h = tt / 3, k = tt % 3;
        const float* a = isD ? a1d : a1s;
        float s = 0.f;
        for (int c = 0; c < 64; c++) s += W1[k * HC + h * 64 + c] * a[h * 64 + c];
        wprep[t] = s;  // [0..23]=ws1[h*3+k], [24..47]=wd1
    }
}

// ---------------- CSR build ----------------
__global__ void k_deg(const int* __restrict__ ei, int* __restrict__ deg) {
    int i = blockIdx.x * 256 + threadIdx.x;
    if (i >= EP) return;
    int d = (i < N_EDGES) ? ei[N_EDGES + i] : (i - N_EDGES);
    atomicAdd(&deg[d], 1);
}

__global__ void k_scan1(const int* __restrict__ deg, int* __restrict__ rowptr, int* __restrict__ part) {
    __shared__ int s[256];
    int t = threadIdx.x, i = blockIdx.x * 256 + t;
    int v = (i < N_NODES) ? deg[i] : 0;
    s[t] = v;
    __syncthreads();
    for (int off = 1; off < 256; off <<= 1) {
        int u = (t >= off) ? s[t - off] : 0;
        __syncthreads();
        s[t] += u;
        __syncthreads();
    }
    if (i < N_NODES) rowptr[i] = s[t] - v;  // exclusive
    if (t == 255) part[blockIdx.x] = s[t];
}

__global__ void k_scan2(int* __restrict__ part, int* __restrict__ rowptr) {
    __shared__ int s[512];
    int t = threadIdx.x;
    int v = (t < SCAN_BLOCKS) ? part[t] : 0;
    s[t] = v;
    __syncthreads();
    for (int off = 1; off < 512; off <<= 1) {
        int u = (t >= off) ? s[t - off] : 0;
        __syncthreads();
        s[t] += u;
        __syncthreads();
    }
    part[t] = s[t] - v;  // exclusive
    if (t == 0) rowptr[N_NODES] = EP;
}

__global__ void k_scan3(const int* __restrict__ part, int* __restrict__ rowptr, int* __restrict__ cursor) {
    int i = blockIdx.x * 256 + threadIdx.x;
    if (i < N_NODES) {
        int v = rowptr[i] + part[blockIdx.x];
        rowptr[i] = v;
        cursor[i] = v;   // scatter cursor starts at row base (no memset needed)
    }
}

__global__ void k_scatter(const int* __restrict__ ei, int* __restrict__ cursor, int* __restrict__ csr) {
    int i = blockIdx.x * 256 + threadIdx.x;
    if (i >= EP) return;
    int s, d;
    if (i < N_EDGES) { s = ei[i]; d = ei[N_EDGES + i]; }
    else { s = i - N_EDGES; d = s; }
    int pos = atomicAdd(&cursor[d], 1);
    csr[pos] = s;
}

// ---------------- W2 -> bf16 transposed with k-permutation matching x1p layout ----------------
// x1p[.][kp] = x1[.][(kp&7)*64 + (kp>>3)]  =>  W2T[n][kp] = W2[(kp&7)*64 + (kp>>3)][n]
__global__ void k_w2t(const float* __restrict__ W2, bf16_t* __restrict__ W2T) {
    int i = blockIdx.x * 256 + threadIdx.x;  // over 512*512
    int n = i >> 9, kp = i & 511;
    int k = (kp & 7) * 64 + (kp >> 3);
    W2T[i] = f2bf(W2[k * HC + n]);
}

// ---------------- layer 1: single-pass softmax (logits provably tiny, no max shift) ---------
// output stored k-PERMUTED: x1p[dst][lane*8+h] = x1[dst][h*64+lane]  (uint4 store)
__global__ __launch_bounds__(256) void k_layer1(
    const float* __restrict__ x, const int* __restrict__ rowptr, const int* __restrict__ csr,
    const float* __restrict__ W1, const float* __restrict__ wprep, const float* __restrict__ b1,
    bf16_t* __restrict__ x1p) {
    __shared__ float w1s[1536];
    __shared__ float wp[48];
    int tid = threadIdx.x;
    for (int i = tid; i < 1536; i += 256) w1s[i] = W1[i];
    if (tid < 48) wp[tid] = wprep[tid];
    __syncthreads();
    int lane = tid & 63;
    int dst = (blockIdx.x * 256 + tid) >> 6;
    int rs = rowptr[dst], re = rowptr[dst + 1];
    float xd0 = x[dst * 3], xd1 = x[dst * 3 + 1], xd2 = x[dst * 3 + 2];
    float ald[NH];
#pragma unroll
    for (int h = 0; h < NH; h++)
        ald[h] = xd0 * wp[24 + h * 3] + xd1 * wp[24 + h * 3 + 1] + xd2 * wp[24 + h * 3 + 2];
    float den[NH], c0[NH], c1[NH], c2[NH];
#pragma unroll
    for (int h = 0; h < NH; h++) { den[h] = 0.f; c0[h] = 0.f; c1[h] = 0.f; c2[h] = 0.f; }
    for (int base = rs; base < re; base += 64) {
        int e = base + lane;
        if (e < re) {
            int s = csr[e];
            float s0 = x[s * 3], s1 = x[s * 3 + 1], s2 = x[s * 3 + 2];
#pragma unroll
            for (int h = 0; h < NH; h++) {
                float ev = s0 * wp[h * 3] + s1 * wp[h * 3 + 1] + s2 * wp[h * 3 + 2] + ald[h];
                ev = fmaxf(ev, 0.2f * ev);
                float w = __expf(ev);      // |ev| <= ~1.2, no overflow risk
                den[h] += w;
                c0[h] += w * s0;
                c1[h] += w * s1;
                c2[h] += w * s2;
            }
        }
    }
#pragma unroll
    for (int h = 0; h < NH; h++) {
#pragma unroll
        for (int off = 1; off < 64; off <<= 1) {
            den[h] += __shfl_xor(den[h], off, 64);
            c0[h] += __shfl_xor(c0[h], off, 64);
            c1[h] += __shfl_xor(c1[h], off, 64);
            c2[h] += __shfl_xor(c2[h], off, 64);
        }
    }
    bf16_t vb[NH];
#pragma unroll
    for (int h = 0; h < NH; h++) {
        int col = h * 64 + lane;
        float v = c0[h] * w1s[col] + c1[h] * w1s[512 + col] + c2[h] * w1s[1024 + col];
        v = v / den[h] + b1[col];
        v = v > 0.f ? v : (__expf(v) - 1.f);
        vb[h] = f2bf(v);
    }
    uint4 o;
    o.x = (unsigned int)vb[0] | ((unsigned int)vb[1] << 16);
    o.y = (unsigned int)vb[2] | ((unsigned int)vb[3] << 16);
    o.z = (unsigned int)vb[4] | ((unsigned int)vb[5] << 16);
    o.w = (unsigned int)vb[6] | ((unsigned int)vb[7] << 16);
    *(uint4*)&x1p[(size_t)dst * HC + lane * 8] = o;
}

// ---------------- GEMM2: h2 = x1p @ W2 (bf16 MFMA), NATURAL col output (coalesced) ----------
__global__ __launch_bounds__(256) void k_gemm2(const bf16_t* __restrict__ A,
                                               const bf16_t* __restrict__ BT,
                                               bf16_t* __restrict__ Out,
                                               int row_base, int nrows) {
    __shared__ short As[128 * ASTRIDE];
    __shared__ short Bs[128 * ASTRIDE];
    int tid = threadIdx.x;
    int lane = tid & 63, wave = tid >> 6;
    int wm = wave & 1, wn = wave >> 1;
    int lm = lane & 15, quad = lane >> 4;
    int gx = blockIdx.x, gy = blockIdx.y;
    floatx4 acc[4][4];
#pragma unroll
    for (int mi = 0; mi < 4; mi++)
#pragma unroll
        for (int ni = 0; ni < 4; ni++) acc[mi][ni] = (floatx4){0.f, 0.f, 0.f, 0.f};

    for (int k0 = 0; k0 < HC; k0 += 32) {
        uint4 av[2], bv[2];
        int rr[2], pp[2];
#pragma unroll
        for (int q = 0; q < 2; q++) {
            int c = tid * 2 + q;
            rr[q] = c >> 2;
            pp[q] = c & 3;
            int grow = gy * 128 + rr[q];
            if (grow < nrows)
                av[q] = *(const uint4*)&A[(size_t)(row_base + grow) * HC + k0 + pp[q] * 8];
            else { av[q].x = 0u; av[q].y = 0u; av[q].z = 0u; av[q].w = 0u; }
            bv[q] = *(const uint4*)&BT[(size_t)(gx * 128 + rr[q]) * HC + k0 + pp[q] * 8];
        }
        __syncthreads();
#pragma unroll
        for (int q = 0; q < 2; q++) {
            *(uint4*)&As[rr[q] * ASTRIDE + pp[q] * 8] = av[q];
            *(uint4*)&Bs[rr[q] * ASTRIDE + pp[q] * 8] = bv[q];
        }
        __syncthreads();
        short8 af[4], bf[4];
#pragma unroll
        for (int mi = 0; mi < 4; mi++)
            af[mi] = *(const short8*)&As[(wm * 64 + mi * 16 + lm) * ASTRIDE + quad * 8];
#pragma unroll
        for (int ni = 0; ni < 4; ni++)
            bf[ni] = *(const short8*)&Bs[(wn * 64 + ni * 16 + lm) * ASTRIDE + quad * 8];
#pragma unroll
        for (int mi = 0; mi < 4; mi++)
#pragma unroll
            for (int ni = 0; ni < 4; ni++)
                acc[mi][ni] = __builtin_amdgcn_mfma_f32_16x16x32_bf16(af[mi], bf[ni], acc[mi][ni], 0, 0, 0);
    }
    // epilogue: C row = quad*4+reg (m), col = natural n (consecutive across lm -> coalesced)
#pragma unroll
    for (int mi = 0; mi < 4; mi++)
#pragma unroll
        for (int ni = 0; ni < 4; ni++) {
            int col = gx * 128 + wn * 64 + ni * 16 + lm;
#pragma unroll
            for (int rg = 0; rg < 4; rg++) {
                int lrow = gy * 128 + wm * 64 + mi * 16 + quad * 4 + rg;
                if (lrow < nrows) Out[(size_t)lrow * HC + col] = f2bf(acc[mi][ni][rg]);
            }
        }
}

// ---------------- al2: per-node logits from NATURAL h2 (read-only) ----------------
// lane covers channels lane*8..lane*8+7, all of head hme = lane>>3
__global__ __launch_bounds__(256) void k_al2(const bf16_t* __restrict__ h2,
                                             const float* __restrict__ a2s,
                                             const float* __restrict__ a2d,
                                             float* __restrict__ al2s, float* __restrict__ al2d) {
    int tid = threadIdx.x, lane = tid & 63, wave = tid >> 6;
    int node = blockIdx.x * 4 + wave;
    uint4 v = *(const uint4*)&h2[(size_t)node * HC + lane * 8];
    float f[8] = {u2flo(v.x), u2fhi(v.x), u2flo(v.y), u2fhi(v.y),
                  u2flo(v.z), u2fhi(v.z), u2flo(v.w), u2fhi(v.w)};
    float4 sa = *(const float4*)&a2s[lane * 8];
    float4 sb = *(const float4*)&a2s[lane * 8 + 4];
    float4 da = *(const float4*)&a2d[lane * 8];
    float4 db = *(const float4*)&a2d[lane * 8 + 4];
    float ps = f[0] * sa.x + f[1] * sa.y + f[2] * sa.z + f[3] * sa.w
             + f[4] * sb.x + f[5] * sb.y + f[6] * sb.z + f[7] * sb.w;
    float pd = f[0] * da.x + f[1] * da.y + f[2] * da.z + f[3] * da.w
             + f[4] * db.x + f[5] * db.y + f[6] * db.z + f[7] * db.w;
#pragma unroll
    for (int off = 1; off < 8; off <<= 1) {   // reduce within 8-lane head group
        ps += __shfl_xor(ps, off, 64);
        pd += __shfl_xor(pd, off, 64);
    }
    if ((lane & 7) == 0) {
        al2s[node * NH + (lane >> 3)] = ps;
        al2d[node * NH + (lane >> 3)] = pd;
    }
}

// ---------------- layer 2 (NATURAL layout): softmax + aggregation + fused mean-pool ---------
__global__ __launch_bounds__(256) void k_layer2pool(
    const bf16_t* __restrict__ h2, const float* __restrict__ al2s, const float* __restrict__ al2d,
    const int* __restrict__ rowptr, const int* __restrict__ csr, const float* __restrict__ b2,
    const int* __restrict__ batch, float* __restrict__ poolpart) {
    __shared__ float wlds[4][512];
    __shared__ int slds[4][64];
    int tid = threadIdx.x, lane = tid & 63, wave = tid >> 6;
    int hme = lane >> 3;
    int dst = blockIdx.x * 4 + wave;
    int rs = rowptr[dst], re = rowptr[dst + 1];
    float4 d0 = *(const float4*)&al2d[dst * NH];
    float4 d1 = *(const float4*)&al2d[dst * NH + 4];
    float ald[NH] = {d0.x, d0.y, d0.z, d0.w, d1.x, d1.y, d1.z, d1.w};
    float den[NH], acc[8];
#pragma unroll
    for (int h = 0; h < NH; h++) den[h] = 0.f;
#pragma unroll
    for (int q = 0; q < 8; q++) acc[q] = 0.f;
    for (int base = rs; base < re; base += 64) {
        int e = base + lane;
        int cl = re - base; if (cl > 64) cl = 64;
        float w[NH];
        int s = 0;
        if (e < re) {
            s = csr[e];
            float4 p0 = *(const float4*)&al2s[s * NH];
            float4 p1 = *(const float4*)&al2s[s * NH + 4];
            float als[NH] = {p0.x, p0.y, p0.z, p0.w, p1.x, p1.y, p1.z, p1.w};
#pragma unroll
            for (int h = 0; h < NH; h++) {
                float ev = als[h] + ald[h];
                ev = fmaxf(ev, 0.2f * ev);
                w[h] = __expf(ev);        // |ev| small, no overflow risk
                den[h] += w[h];
            }
        } else {
#pragma unroll
            for (int h = 0; h < NH; h++) w[h] = 0.f;
        }
        slds[wave][lane] = s;
        *(float4*)&wlds[wave][lane * 8] = make_float4(w[0], w[1], w[2], w[3]);
        *(float4*)&wlds[wave][lane * 8 + 4] = make_float4(w[4], w[5], w[6], w[7]);
        // same-wave LDS write->read in program order; scalar weight broadcast per lane group
        int j = 0;
        for (; j + 3 < cl; j += 4) {
            int s0 = slds[wave][j + 0], s1 = slds[wave][j + 1];
            int s2 = slds[wave][j + 2], s3 = slds[wave][j + 3];
            float w0 = wlds[wave][(j + 0) * 8 + hme];
            float w1 = wlds[wave][(j + 1) * 8 + hme];
            float w2 = wlds[wave][(j + 2) * 8 + hme];
            float w3 = wlds[wave][(j + 3) * 8 + hme];
            uint4 v0 = *(const uint4*)&h2[(size_t)s0 * HC + lane * 8];
            uint4 v1 = *(const uint4*)&h2[(size_t)s1 * HC + lane * 8];
            uint4 v2 = *(const uint4*)&h2[(size_t)s2 * HC + lane * 8];
            uint4 v3 = *(const uint4*)&h2[(size_t)s3 * HC + lane * 8];
            acc[0] += w0 * u2flo(v0.x); acc[1] += w0 * u2fhi(v0.x);
            acc[2] += w0 * u2flo(v0.y); acc[3] += w0 * u2fhi(v0.y);
            acc[4] += w0 * u2flo(v0.z); acc[5] += w0 * u2fhi(v0.z);
            acc[6] += w0 * u2flo(v0.w); acc[7] += w0 * u2fhi(v0.w);
            acc[0] += w1 * u2flo(v1.x); acc[1] += w1 * u2fhi(v1.x);
            acc[2] += w1 * u2flo(v1.y); acc[3] += w1 * u2fhi(v1.y);
            acc[4] += w1 * u2flo(v1.z); acc[5] += w1 * u2fhi(v1.z);
            acc[6] += w1 * u2flo(v1.w); acc[7] += w1 * u2fhi(v1.w);
            acc[0] += w2 * u2flo(v2.x); acc[1] += w2 * u2fhi(v2.x);
            acc[2] += w2 * u2flo(v2.y); acc[3] += w2 * u2fhi(v2.y);
            acc[4] += w2 * u2flo(v2.z); acc[5] += w2 * u2fhi(v2.z);
            acc[6] += w2 * u2flo(v2.w); acc[7] += w2 * u2fhi(v2.w);
            acc[0] += w3 * u2flo(v3.x); acc[1] += w3 * u2fhi(v3.x);
            acc[2] += w3 * u2flo(v3.y); acc[3] += w3 * u2fhi(v3.y);
            acc[4] += w3 * u2flo(v3.z); acc[5] += w3 * u2fhi(v3.z);
            acc[6] += w3 * u2flo(v3.w); acc[7] += w3 * u2fhi(v3.w);
        }
        for (; j < cl; j++) {
            int sA = slds[wave][j];
            float wA = wlds[wave][j * 8 + hme];
            uint4 vA = *(const uint4*)&h2[(size_t)sA * HC + lane * 8];
            acc[0] += wA * u2flo(vA.x); acc[1] += wA * u2fhi(vA.x);
            acc[2] += wA * u2flo(vA.y); acc[3] += wA * u2fhi(vA.y);
            acc[4] += wA * u2flo(vA.z); acc[5] += wA * u2fhi(vA.z);
            acc[6] += wA * u2flo(vA.w); acc[7] += wA * u2fhi(vA.w);
        }
    }
#pragma unroll
    for (int h = 0; h < NH; h++)
#pragma unroll
        for (int off = 1; off < 64; off <<= 1) den[h] += __shfl_xor(den[h], off, 64);
    // select this lane's head denominator (no dynamic register indexing)
    float dd = den[0];
#pragma unroll
    for (int h = 1; h < NH; h++) dd = (hme == h) ? den[h] : dd;
    float dinv = 1.0f / dd;
    float4 ba = *(const float4*)&b2[lane * 8];
    float4 bb = *(const float4*)&b2[lane * 8 + 4];
    float bv[8] = {ba.x, ba.y, ba.z, ba.w, bb.x, bb.y, bb.z, bb.w};
    // stage post-ELU values in LDS, then atomics in COALESCED (h*64+lane) order:
    // 64 lanes hit 256 contiguous bytes per instruction (4 cachelines, not 32)
#pragma unroll
    for (int q = 0; q < 8; q++) {
        float v = acc[q] * dinv + bv[q];
        v = v > 0.f ? v : (__expf(v) - 1.f);
        wlds[wave][lane * 8 + q] = v;
    }
    int g = batch[dst];
    float* pp = poolpart + ((size_t)(blockIdx.x & (NPART - 1)) * NG + g) * HC;
#pragma unroll
    for (int h = 0; h < NH; h++)
        atomicAdd(&pp[h * 64 + lane], wlds[wave][h * 64 + lane]);
}

// ---------------- graph bounds ----------------
__global__ void k_initb(int* __restrict__ gstart) {
    int i = blockIdx.x * 64 + threadIdx.x;
    if (i <= NG) gstart[i] = N_NODES;
}

__global__ void k_bounds(const int* __restrict__ batch, int* __restrict__ gstart) {
    int i = blockIdx.x * 256 + threadIdx.x;
    if (i >= N_NODES) return;
    int b = batch[i];
    if (i == 0) {
        for (int g = 0; g <= b; g++) gstart[g] = 0;
    } else {
        int bp = batch[i - 1];
        if (b != bp)
            for (int g = bp + 1; g <= b; g++) gstart[g] = i;
    }
}

// ---------------- reduce pooling partitions ----------------
__global__ void k_poolred(const float* __restrict__ poolpart, float* __restrict__ pooled) {
    int i = blockIdx.x * 256 + threadIdx.x;
    if (i >= NG * HC) return;
    float s = 0.f;
    for (int p = 0; p < NPART; p++) s += poolpart[(size_t)p * NG * HC + i];
    pooled[i] = s;
}

// ---------------- classifier ----------------
__global__ void k_cls(const float* __restrict__ pooled, const int* __restrict__ gstart,
                      const float* __restrict__ Wc, const float* __restrict__ bc,
                      float* __restrict__ out) {
    int i = blockIdx.x * 256 + threadIdx.x;
    if (i >= NG * 10) return;
    int g = i / 10, o = i % 10;
    float cnt = fmaxf((float)(gstart[g + 1] - gstart[g]), 1.0f);
    float acc = 0.f;
    for (int k = 0; k < HC; k++) acc += pooled[g * HC + k] * Wc[k * 10 + o];
    out[i] = acc / cnt + bc[o];
}

extern "C" void kernel_launch(void* const* d_in, const int* in_sizes, int n_in,
                              void* d_out, int out_size, void* d_ws, size_t ws_size,
                              hipStream_t stream) {
    const float* x   = (const float*)d_in[0];
    const int*   ei  = (const int*)d_in[1];
    const int*   bat = (const int*)d_in[2];
    const float* W1  = (const float*)d_in[3];
    const float* a1s = (const float*)d_in[4];
    const float* a1d = (const float*)d_in[5];
    const float* b1  = (const float*)d_in[6];
    const float* W2  = (const float*)d_in[7];
    const float* a2s = (const float*)d_in[8];
    const float* a2d = (const float*)d_in[9];
    const float* b2  = (const float*)d_in[10];
    const float* Wc  = (const float*)d_in[11];
    const float* bc  = (const float*)d_in[12];
    float* out = (float*)d_out;

    char* ws = (char*)d_ws;
    size_t off = 0;
    auto alloc = [&](size_t bytes) {
        size_t o = off;
        off += (bytes + 255) & ~(size_t)255;
        return o;
    };
    float*  wprep    = (float*)(ws + alloc(48 * 4));
    int*    rowptr   = (int*)(ws + alloc((size_t)(N_NODES + 1) * 4));
    int*    deg      = (int*)(ws + alloc((size_t)N_NODES * 4));
    int*    cursor   = (int*)(ws + alloc((size_t)N_NODES * 4));
    int*    part     = (int*)(ws + alloc(512 * 4));
    int*    gstart   = (int*)(ws + alloc(65 * 4));
    int*    csr      = (int*)(ws + alloc((size_t)EP * 4));
    bf16_t* x1b      = (bf16_t*)(ws + alloc((size_t)N_NODES * HC * 2));
    float*  al2s     = (float*)(ws + alloc((size_t)N_NODES * NH * 4));
    float*  al2d     = (float*)(ws + alloc((size_t)N_NODES * NH * 4));
    float*  poolpart = (float*)(ws + alloc((size_t)NPART * NG * HC * 4));
    float*  pooled   = (float*)(ws + alloc((size_t)NG * HC * 4));
    // W2T (512KB) aliases deg+cursor (800KB, dead after k_scatter)
    bf16_t* W2T = (bf16_t*)deg;

    size_t rem = (ws_size > off) ? ws_size - off : 0;
    int nslices, srows;
    if (rem >= (size_t)N_NODES * HC * 2)      { nslices = 1;  srows = N_NODES; }
    else if (rem >= (size_t)25000 * HC * 2)   { nslices = 4;  srows = 25000; }
    else                                      { nslices = 16; srows = 6250; }
    bf16_t* T = (bf16_t*)(ws + alloc((size_t)srows * HC * 2));
    bf16_t* h2 = (nslices == 1) ? T : x1b;

    hipMemsetAsync(deg, 0, (size_t)N_NODES * 4, stream);
    hipMemsetAsync(poolpart, 0, (size_t)NPART * NG * HC * 4, stream);

    k_prep<<<1, 64, 0, stream>>>(W1, a1s, a1d, wprep);
    k_deg<<<(EP + 255) / 256, 256, 0, stream>>>(ei, deg);
    k_scan1<<<SCAN_BLOCKS, 256, 0, stream>>>(deg, rowptr, part);
    k_scan2<<<1, 512, 0, stream>>>(part, rowptr);
    k_scan3<<<SCAN_BLOCKS, 256, 0, stream>>>(part, rowptr, cursor);
    k_scatter<<<(EP + 255) / 256, 256, 0, stream>>>(ei, cursor, csr);
    k_w2t<<<(HC * HC + 255) / 256, 256, 0, stream>>>(W2, W2T);  // aliases deg/cursor (dead)
    k_layer1<<<N_NODES / 4, 256, 0, stream>>>(x, rowptr, csr, W1, wprep, b1, x1b);
    if (nslices == 1) {
        k_gemm2<<<dim3(4, (N_NODES + 127) / 128), 256, 0, stream>>>(x1b, W2T, h2, 0, N_NODES);
    } else {
        for (int s = 0; s < nslices; s++) {
            k_gemm2<<<dim3(4, (srows + 127) / 128), 256, 0, stream>>>(x1b, W2T, T, s * srows, srows);
            hipMemcpyAsync(x1b + (size_t)s * srows * HC, T, (size_t)srows * HC * 2,
                           hipMemcpyDeviceToDevice, stream);
        }
    }
    k_al2<<<N_NODES / 4, 256, 0, stream>>>(h2, a2s, a2d, al2s, al2d);
    k_initb<<<2, 64, 0, stream>>>(gstart);
    k_bounds<<<SCAN_BLOCKS, 256, 0, stream>>>(bat, gstart);
    k_layer2pool<<<N_NODES / 4, 256, 0, stream>>>(h2, al2s, al2d, rowptr, csr, b2, bat, poolpart);
    k_poolred<<<(NG * HC + 255) / 256, 256, 0, stream>>>(poolpart, pooled);
    k_cls<<<3, 256, 0, stream>>>(pooled, gstart, Wc, bc, out);
}